// Round 12
// baseline (2439.875 us; speedup 1.0000x reference)
//
#include <hip/hip_runtime.h>
#include <math.h>

#define HD 2048
#define NACT 16
#define NSTEP 24
#define WL (4*HD*HD)        // per-layer per-matrix elems (16,777,216)
#define NIH (2*WL)          // elems in w_ih (both layers) = 33,554,432

#define NWG 256             // proven co-resident (1 block/CU)
#define NTHR 512            // 8 waves: 1 wave per hidden unit, full-K
#define NWG_FB 256
#define NTHR_FB 512

typedef float  nf4 __attribute__((ext_vector_type(4)));   // native vec for NT builtins

// ---------------- agent-scope (cross-XCD coherent) access helpers ----------------
__device__ __forceinline__ float ld_agent(const float* p) {
  return __hip_atomic_load(p, __ATOMIC_RELAXED, __HIP_MEMORY_SCOPE_AGENT);
}
__device__ __forceinline__ void st_agent(float* p, float v) {
  __hip_atomic_store(p, v, __ATOMIC_RELAXED, __HIP_MEMORY_SCOPE_AGENT);
}

// ---------------- threefry2x32-20 (JAX partitionable semantics) ----------------
__device__ __forceinline__ unsigned rotl32(unsigned v, int r) { return (v << r) | (v >> (32 - r)); }

__device__ __forceinline__ void threefry(unsigned k0, unsigned k1, unsigned x0, unsigned x1,
                                         unsigned& o0, unsigned& o1) {
  unsigned ks2 = k0 ^ k1 ^ 0x1BD11BDAu;
#define TFR(r) { x0 += x1; x1 = rotl32(x1, r); x1 ^= x0; }
  x0 += k0; x1 += k1;
  TFR(13) TFR(15) TFR(26) TFR(6)
  x0 += k1;  x1 += ks2 + 1u;
  TFR(17) TFR(29) TFR(16) TFR(24)
  x0 += ks2; x1 += k0 + 2u;
  TFR(13) TFR(15) TFR(26) TFR(6)
  x0 += k0;  x1 += k1 + 3u;
  TFR(17) TFR(29) TFR(16) TFR(24)
  x0 += k1;  x1 += ks2 + 4u;
  TFR(13) TFR(15) TFR(26) TFR(6)
  x0 += ks2; x1 += k0 + 5u;
#undef TFR
  o0 = x0; o1 = x1;
}

__device__ __forceinline__ float sigmoidf(float x) { return 1.0f / (1.0f + expf(-x)); }

// bf16 helpers
__device__ __forceinline__ unsigned f2bf(float f) {          // round-to-nearest-even
  unsigned u = __float_as_uint(f);
  return (u + 0x7fffu + ((u >> 16) & 1u)) >> 16;
}
#define BF_LO(u) __uint_as_float((u) << 16)
#define BF_HI(u) __uint_as_float((u) & 0xffff0000u)

// ---------------- flag-array grid barrier, fence-free (256 wgs) ----------------
__device__ void grid_bar(unsigned* flags, unsigned ep) {
  __syncthreads();
  if (threadIdx.x == 0) {
    __hip_atomic_store(&flags[blockIdx.x], ep, __ATOMIC_RELAXED, __HIP_MEMORY_SCOPE_AGENT);
  }
  if (threadIdx.x < 64) {
    const unsigned* my = flags + threadIdx.x * 4;
    long guard = 0;
    for (;;) {
      unsigned f0 = __hip_atomic_load(my + 0, __ATOMIC_RELAXED, __HIP_MEMORY_SCOPE_AGENT);
      unsigned f1 = __hip_atomic_load(my + 1, __ATOMIC_RELAXED, __HIP_MEMORY_SCOPE_AGENT);
      unsigned f2 = __hip_atomic_load(my + 2, __ATOMIC_RELAXED, __HIP_MEMORY_SCOPE_AGENT);
      unsigned f3 = __hip_atomic_load(my + 3, __ATOMIC_RELAXED, __HIP_MEMORY_SCOPE_AGENT);
      bool ok = (f0 >= ep) && (f1 >= ep) && (f2 >= ep) && (f3 >= ep);
      if (__all(ok)) break;
      if (++guard > 2000000L) break;
      __builtin_amdgcn_s_sleep(8);
    }
  }
  __syncthreads();
}

// ---------------- logits + categorical sample (redundant per wg, 8 waves) ----------------
__device__ int sample_step(const float* __restrict__ h1g, const float* __restrict__ soft_w,
                           int t, float* lp_out, float* ent_out) {
  __shared__ float s_part[8][NACT];
  __shared__ float s_res[3];
  const int wave = threadIdx.x >> 6;
  const int lane = threadIdx.x & 63;

  float lg[NACT];
#pragma unroll
  for (int a = 0; a < NACT; ++a) lg[a] = 0.0f;
#pragma unroll
  for (int m = 0; m < 4; ++m) {
    int e = wave * 256 + m * 64 + lane;
    float hv = ld_agent(h1g + e);          // cross-wg h -> coherent load
    const float* sw = soft_w + (size_t)e * NACT;
    float4 r0 = *(const float4*)(sw);
    float4 r1 = *(const float4*)(sw + 4);
    float4 r2 = *(const float4*)(sw + 8);
    float4 r3 = *(const float4*)(sw + 12);
    lg[0]  += hv * r0.x; lg[1]  += hv * r0.y; lg[2]  += hv * r0.z; lg[3]  += hv * r0.w;
    lg[4]  += hv * r1.x; lg[5]  += hv * r1.y; lg[6]  += hv * r1.z; lg[7]  += hv * r1.w;
    lg[8]  += hv * r2.x; lg[9]  += hv * r2.y; lg[10] += hv * r2.z; lg[11] += hv * r2.w;
    lg[12] += hv * r3.x; lg[13] += hv * r3.y; lg[14] += hv * r3.z; lg[15] += hv * r3.w;
  }
#pragma unroll
  for (int off = 32; off > 0; off >>= 1) {
#pragma unroll
    for (int a = 0; a < NACT; ++a) lg[a] += __shfl_xor(lg[a], off, 64);
  }
  if (lane == 0) {
#pragma unroll
    for (int a = 0; a < NACT; ++a) s_part[wave][a] = lg[a];
  }
  __syncthreads();

  if (wave == 0 && lane < NACT) {
    float logit = 0.0f;
#pragma unroll
    for (int w = 0; w < 8; ++w) logit += s_part[w][lane];

    unsigned kt0, kt1, b0, b1;
    threefry(0u, 42u, 0u, (unsigned)t, kt0, kt1);
    threefry(kt0, kt1, 0u, (unsigned)lane, b0, b1);
    unsigned bits = b0 ^ b1;

    const float tiny = 1.17549435e-38f;
    float u = __uint_as_float((bits >> 9) | 0x3f800000u) - 1.0f;  // [0,1)
    u = fmaxf(tiny, u + tiny);
    float gmb = -logf(-logf(u));
    float z = logit + gmb;

    int idx = lane; float zz = z;
#pragma unroll
    for (int off = 8; off > 0; off >>= 1) {
      float oz = __shfl_xor(zz, off, NACT);
      int   oi = __shfl_xor(idx, off, NACT);
      if (oz > zz || (oz == zz && oi < idx)) { zz = oz; idx = oi; }
    }
    float mx = logit;
#pragma unroll
    for (int off = 8; off > 0; off >>= 1) mx = fmaxf(mx, __shfl_xor(mx, off, NACT));
    float sh = logit - mx;
    float se = expf(sh);
#pragma unroll
    for (int off = 8; off > 0; off >>= 1) se += __shfl_xor(se, off, NACT);
    float lp = sh - logf(se);
    float term = expf(lp) * lp;
#pragma unroll
    for (int off = 8; off > 0; off >>= 1) term += __shfl_xor(term, off, NACT);
    float lp_sel = __shfl(lp, idx, NACT);
    if (lane == 0) { s_res[0] = (float)idx; s_res[1] = lp_sel; s_res[2] = -term; }
  }
  __syncthreads();
  int act = (int)s_res[0];
  *lp_out = s_res[1];
  *ent_out = s_res[2];
  return act;
}

// =======================================================================
//                     FAST PATH: bf16 weights in d_ws
// =======================================================================

// f32 -> bf16 conversion, 8 elems/thread. NT loads for the single-use f32 stream.
__global__ void __launch_bounds__(256) conv_bf16(const float* __restrict__ src,
                                                 unsigned* __restrict__ dst) {
  size_t i = ((size_t)blockIdx.x * blockDim.x + threadIdx.x) * 8;
  const nf4* s4 = (const nf4*)(src + i);
  nf4 a = __builtin_nontemporal_load(s4);
  nf4 b = __builtin_nontemporal_load(s4 + 1);
  uint4 o;
  o.x = (f2bf(a.y) << 16) | f2bf(a.x);
  o.y = (f2bf(a.w) << 16) | f2bf(a.z);
  o.z = (f2bf(b.y) << 16) | f2bf(b.x);
  o.w = (f2bf(b.w) << 16) | f2bf(b.z);
  *(uint4*)(dst + i / 2) = o;
}

// ---- issue the full weight set of one layer-phase into registers ----
// 4 gates x 2 matrices x 8 chunks of uint2 (4 bf16 each) = 128 VGPRs.
// Issued BEFORE the grid barrier: the barrier's entry drain makes these
// loads stream during the barrier window (free registers: block-count-
// limited occupancy leaves ~256 VGPR/wave available).
__device__ __forceinline__ void prefetch_w(const unsigned* __restrict__ wiL,
                                           const unsigned* __restrict__ whL,
                                           int j, int lane,
                                           uint2 A[4][8], uint2 B[4][8]) {
#pragma unroll
  for (int g = 0; g < 4; ++g) {
    const unsigned* wi = wiL + ((size_t)(g * HD + j) * HD >> 1) + lane * 2;
    const unsigned* wh = whL + ((size_t)(g * HD + j) * HD >> 1) + lane * 2;
#pragma unroll
    for (int k = 0; k < 8; ++k) {
      A[g][k] = *(const uint2*)(wi + k * 128);
      B[g][k] = *(const uint2*)(wh + k * 128);
    }
  }
}

// ---- cooperative x/h stage into LDS (after barrier) ----
__device__ __forceinline__ void stage_xh(const float* __restrict__ x, bool x_is_shared,
                                         const float* __restrict__ hin,
                                         float* s_x, float* s_h, int tid) {
#pragma unroll
  for (int r = 0; r < 4; ++r) {
    int e = tid + r * 512;
    s_x[e] = x_is_shared ? ld_agent(x + e) : x[e];
    s_h[e] = ld_agent(hin + e);
  }
  __syncthreads();
}

// ---- consume prefetched weights + LDS x/h; write unit's h/c ----
__device__ __forceinline__ void layer_compute(const float* __restrict__ bihL,
                                              const float* __restrict__ bhhL,
                                              const float* s_x, const float* s_h,
                                              float* __restrict__ hout, float* __restrict__ c,
                                              int j, int lane,
                                              const uint2 A[4][8], const uint2 B[4][8]) {
  float acc[4];
#pragma unroll
  for (int g = 0; g < 4; ++g) {
    float si = 0.0f, sh2 = 0.0f;
#pragma unroll
    for (int k = 0; k < 8; ++k) {
      float4 xv = *(const float4*)(s_x + k * 256 + lane * 4);   // dense, conflict-free
      float4 hv = *(const float4*)(s_h + k * 256 + lane * 4);
      uint2 qa = A[g][k];
      uint2 qb = B[g][k];
      si  += BF_LO(qa.x) * xv.x + BF_HI(qa.x) * xv.y;
      si  += BF_LO(qa.y) * xv.z + BF_HI(qa.y) * xv.w;
      sh2 += BF_LO(qb.x) * hv.x + BF_HI(qb.x) * hv.y;
      sh2 += BF_LO(qb.y) * hv.z + BF_HI(qb.y) * hv.w;
    }
    acc[g] = si + sh2;
  }
#pragma unroll
  for (int off = 32; off > 0; off >>= 1) {
#pragma unroll
    for (int g = 0; g < 4; ++g) acc[g] += __shfl_xor(acc[g], off, 64);
  }
  if (lane == 0) {
    float gi = acc[0] + bihL[j]          + bhhL[j];
    float gf = acc[1] + bihL[HD + j]     + bhhL[HD + j];
    float gg = acc[2] + bihL[2 * HD + j] + bhhL[2 * HD + j];
    float go = acc[3] + bihL[3 * HD + j] + bhhL[3 * HD + j];
    float cn = sigmoidf(gf) * c[j] + sigmoidf(gi) * tanhf(gg);
    c[j] = cn;                                     // wg-private (same CU)
    st_agent(&hout[j], sigmoidf(go) * tanhf(cn));  // cross-wg coherent
  }
}

__global__ void __launch_bounds__(NTHR, 2)   // 2 waves/EU floor -> 256-VGPR budget
ctrl2_kernel(
    const float* __restrict__ g_emb, const float* __restrict__ w_emb,
    const float* __restrict__ soft_w,
    const unsigned* __restrict__ wb_ih, const unsigned* __restrict__ wb_hh,
    const float* __restrict__ b_ih, const float* __restrict__ b_hh,
    float* __restrict__ out, float* __restrict__ state, unsigned* __restrict__ flags) {
  __shared__ float s_x[HD];
  __shared__ float s_h[HD];
  float* h0 = state;            // [2][HD] ping-pong
  float* h1 = state + 2 * HD;   // [2][HD] ping-pong
  float* c0 = state + 4 * HD;
  float* c1 = state + 5 * HD;

  const int tid  = threadIdx.x;
  const int wave = tid >> 6;
  const int lane = tid & 63;
  const int j = (int)blockIdx.x * 8 + wave;   // hidden unit owned by this wave

  if (tid < 8) {
    int jj = (int)blockIdx.x * 8 + tid;
    st_agent(&h0[jj], 0.0f); st_agent(&h1[jj], 0.0f);
    c0[jj] = 0.0f; c1[jj] = 0.0f;
  }

  const unsigned* wi0 = wb_ih;             const unsigned* wh0 = wb_hh;
  const unsigned* wi1 = wb_ih + WL / 2;    const unsigned* wh1 = wb_hh + WL / 2;

  uint2 A[4][8], B[4][8];
  prefetch_w(wi0, wh0, j, lane, A, B);     // L0 weights stream during init barrier
  unsigned ep = 1;
  grid_bar(flags, ep++);

  const float* x = g_emb;
  for (int t = 0; t < NSTEP; ++t) {
    int q = t & 1;
    // ---- layer 0 ----
    stage_xh(x, /*x shared=*/false, h0 + q * HD, s_x, s_h, tid);
    layer_compute(b_ih, b_hh, s_x, s_h, h0 + (1 - q) * HD, c0, j, lane, A, B);
    prefetch_w(wi1, wh1, j, lane, A, B);   // L1 weights stream during barrier
    grid_bar(flags, ep++);
    // ---- layer 1 ----
    stage_xh(h0 + (1 - q) * HD, /*x shared=*/true, h1 + q * HD, s_x, s_h, tid);
    layer_compute(b_ih + 4 * HD, b_hh + 4 * HD, s_x, s_h,
                  h1 + (1 - q) * HD, c1, j, lane, A, B);
    prefetch_w(wi0, wh0, j, lane, A, B);   // next step's L0 (wasted at t=23, harmless)
    grid_bar(flags, ep++);
    // ---- sample ----
    float lp, en;
    int act = sample_step(h1 + (1 - q) * HD, soft_w, t, &lp, &en);
    if (blockIdx.x == 0 && tid == 0) {
      out[t] = (float)act;
      out[NSTEP + t] = lp;
      out[2 * NSTEP + t] = en;
    }
    x = w_emb + (size_t)act * HD;
  }
}

// =======================================================================
//          FALLBACK PATH: f32 weights direct (round-5-proven, 256x512)
// =======================================================================

__device__ void grid_bar_ctr(unsigned long long* ctr, unsigned long long target) {
  __syncthreads();
  if (threadIdx.x == 0) {
    __builtin_amdgcn_fence(__ATOMIC_SEQ_CST, "agent");
    __hip_atomic_fetch_add(ctr, 1ull, __ATOMIC_RELAXED, __HIP_MEMORY_SCOPE_AGENT);
    long guard = 0;
    while (__hip_atomic_load(ctr, __ATOMIC_RELAXED, __HIP_MEMORY_SCOPE_AGENT) < target &&
           guard < 20000000L) {
      __builtin_amdgcn_s_sleep(2);
      ++guard;
    }
    __builtin_amdgcn_fence(__ATOMIC_SEQ_CST, "agent");
  }
  __syncthreads();
}

__device__ int sample_step8(const float* __restrict__ h1g, const float* __restrict__ soft_w,
                            int t, float* lp_out, float* ent_out) {
  __shared__ float s_part[8][NACT];
  __shared__ float s_res[3];
  const int wave = threadIdx.x >> 6;
  const int lane = threadIdx.x & 63;

  float lg[NACT];
#pragma unroll
  for (int a = 0; a < NACT; ++a) lg[a] = 0.0f;
#pragma unroll
  for (int m = 0; m < 4; ++m) {
    int e = wave * 256 + m * 64 + lane;
    float hv = h1g[e];
    const float* sw = soft_w + (size_t)e * NACT;
    float4 r0 = *(const float4*)(sw);
    float4 r1 = *(const float4*)(sw + 4);
    float4 r2 = *(const float4*)(sw + 8);
    float4 r3 = *(const float4*)(sw + 12);
    lg[0]  += hv * r0.x; lg[1]  += hv * r0.y; lg[2]  += hv * r0.z; lg[3]  += hv * r0.w;
    lg[4]  += hv * r1.x; lg[5]  += hv * r1.y; lg[6]  += hv * r1.z; lg[7]  += hv * r1.w;
    lg[8]  += hv * r2.x; lg[9]  += hv * r2.y; lg[10] += hv * r2.z; lg[11] += hv * r2.w;
    lg[12] += hv * r3.x; lg[13] += hv * r3.y; lg[14] += hv * r3.z; lg[15] += hv * r3.w;
  }
#pragma unroll
  for (int off = 32; off > 0; off >>= 1) {
#pragma unroll
    for (int a = 0; a < NACT; ++a) lg[a] += __shfl_xor(lg[a], off, 64);
  }
  if (lane == 0) {
#pragma unroll
    for (int a = 0; a < NACT; ++a) s_part[wave][a] = lg[a];
  }
  __syncthreads();

  if (wave == 0 && lane < NACT) {
    float logit = 0.0f;
#pragma unroll
    for (int w = 0; w < 8; ++w) logit += s_part[w][lane];
    unsigned kt0, kt1, b0, b1;
    threefry(0u, 42u, 0u, (unsigned)t, kt0, kt1);
    threefry(kt0, kt1, 0u, (unsigned)lane, b0, b1);
    unsigned bits = b0 ^ b1;
    const float tiny = 1.17549435e-38f;
    float u = __uint_as_float((bits >> 9) | 0x3f800000u) - 1.0f;
    u = fmaxf(tiny, u + tiny);
    float gmb = -logf(-logf(u));
    float z = logit + gmb;
    int idx = lane; float zz = z;
#pragma unroll
    for (int off = 8; off > 0; off >>= 1) {
      float oz = __shfl_xor(zz, off, NACT);
      int   oi = __shfl_xor(idx, off, NACT);
      if (oz > zz || (oz == zz && oi < idx)) { zz = oz; idx = oi; }
    }
    float mx = logit;
#pragma unroll
    for (int off = 8; off > 0; off >>= 1) mx = fmaxf(mx, __shfl_xor(mx, off, NACT));
    float sh = logit - mx;
    float se = expf(sh);
#pragma unroll
    for (int off = 8; off > 0; off >>= 1) se += __shfl_xor(se, off, NACT);
    float lp = sh - logf(se);
    float term = expf(lp) * lp;
#pragma unroll
    for (int off = 8; off > 0; off >>= 1) term += __shfl_xor(term, off, NACT);
    float lp_sel = __shfl(lp, idx, NACT);
    if (lane == 0) { s_res[0] = (float)idx; s_res[1] = lp_sel; s_res[2] = -term; }
  }
  __syncthreads();
  int act = (int)s_res[0];
  *lp_out = s_res[1];
  *ent_out = s_res[2];
  return act;
}

__device__ void lstm_layer(const float* __restrict__ Wih, const float* __restrict__ Whh,
                           const float* __restrict__ bih, const float* __restrict__ bhh,
                           const float* __restrict__ x, const float* __restrict__ hin,
                           float* __restrict__ hout, float* __restrict__ c) {
  const int wave = threadIdx.x >> 6;
  const int lane = threadIdx.x & 63;
  const int j = (int)blockIdx.x * 8 + wave;

  float4 xv[8], hv[8];
#pragma unroll
  for (int k = 0; k < 8; ++k) {
    int e = k * 256 + lane * 4;
    xv[k] = *(const float4*)(x + e);
    hv[k] = *(const float4*)(hin + e);
  }
  float acc[4];
#pragma unroll
  for (int g = 0; g < 4; ++g) {
    const float* wi = Wih + (size_t)(g * HD + j) * HD;
    const float* wh = Whh + (size_t)(g * HD + j) * HD;
    float s = 0.0f;
#pragma unroll
    for (int k = 0; k < 8; ++k) {
      int e = k * 256 + lane * 4;
      float4 a4 = *(const float4*)(wi + e);
      float4 b4 = *(const float4*)(wh + e);
      s += a4.x * xv[k].x; s += a4.y * xv[k].y; s += a4.z * xv[k].z; s += a4.w * xv[k].w;
      s += b4.x * hv[k].x; s += b4.y * hv[k].y; s += b4.z * hv[k].z; s += b4.w * hv[k].w;
    }
    acc[g] = s;
  }
#pragma unroll
  for (int off = 32; off > 0; off >>= 1) {
#pragma unroll
    for (int g = 0; g < 4; ++g) acc[g] += __shfl_xor(acc[g], off, 64);
  }
  if (lane == 0) {
    float gi = acc[0] + bih[j]          + bhh[j];
    float gf = acc[1] + bih[HD + j]     + bhh[HD + j];
    float gg = acc[2] + bih[2 * HD + j] + bhh[2 * HD + j];
    float go = acc[3] + bih[3 * HD + j] + bhh[3 * HD + j];
    float cn = sigmoidf(gf) * c[j] + sigmoidf(gi) * tanhf(gg);
    c[j] = cn;
    hout[j] = sigmoidf(go) * tanhf(cn);
  }
}

__global__ void __launch_bounds__(NTHR_FB) ctrl_kernel(
    const float* __restrict__ g_emb, const float* __restrict__ w_emb,
    const float* __restrict__ soft_w, const float* __restrict__ w_ih,
    const float* __restrict__ w_hh, const float* __restrict__ b_ih,
    const float* __restrict__ b_hh, float* __restrict__ out, float* __restrict__ ws) {
  float* h0 = ws;
  float* h1 = ws + 2 * HD;
  float* c0 = ws + 4 * HD;
  float* c1 = ws + 5 * HD;
  unsigned long long* bar = (unsigned long long*)(ws + 6 * HD);

  if (threadIdx.x < 8) {
    int j = (int)blockIdx.x * 8 + (int)threadIdx.x;
    h0[j] = 0.0f; h1[j] = 0.0f; c0[j] = 0.0f; c1[j] = 0.0f;
  }
  unsigned long long ep = 1;
  grid_bar_ctr(bar, (ep++) * NWG_FB);

  const float* x = g_emb;
  for (int t = 0; t < NSTEP; ++t) {
    int q = t & 1;
    lstm_layer(w_ih, w_hh, b_ih, b_hh, x, h0 + q * HD, h0 + (1 - q) * HD, c0);
    grid_bar_ctr(bar, (ep++) * NWG_FB);
    lstm_layer(w_ih + WL, w_hh + WL, b_ih + 4 * HD, b_hh + 4 * HD,
               h0 + (1 - q) * HD, h1 + q * HD, h1 + (1 - q) * HD, c1);
    grid_bar_ctr(bar, (ep++) * NWG_FB);
    float lp, en;
    int act = sample_step8(h1 + (1 - q) * HD, soft_w, t, &lp, &en);
    if (blockIdx.x == 0 && threadIdx.x == 0) {
      out[t] = (float)act;
      out[NSTEP + t] = lp;
      out[2 * NSTEP + t] = en;
    }
    x = w_emb + (size_t)act * HD;
  }
}

__global__ void init_sync(unsigned* flags) {            // zero NWG flags
  flags[threadIdx.x] = 0u;
}
__global__ void init_bar(unsigned long long* bar) { *bar = 0ull; }

extern "C" void kernel_launch(void* const* d_in, const int* in_sizes, int n_in,
                              void* d_out, int out_size, void* d_ws, size_t ws_size,
                              hipStream_t stream) {
  const float* g_emb  = (const float*)d_in[0];
  const float* w_emb  = (const float*)d_in[1];
  const float* soft_w = (const float*)d_in[2];
  const float* w_ih   = (const float*)d_in[3];
  const float* w_hh   = (const float*)d_in[4];
  const float* b_ih   = (const float*)d_in[5];
  const float* b_hh   = (const float*)d_in[6];

  const size_t wbytes = (size_t)NIH * 2 * sizeof(unsigned short);  // 134,217,728
  const size_t need = wbytes + (size_t)6 * HD * sizeof(float) + NWG * sizeof(unsigned) + 64;

  if (ws_size >= need) {
    unsigned* wb_ih = (unsigned*)d_ws;               // NIH bf16 = NIH/2 uints
    unsigned* wb_hh = wb_ih + NIH / 2;
    float* state = (float*)((char*)d_ws + wbytes);
    unsigned* flags = (unsigned*)(state + 6 * HD);

    hipLaunchKernelGGL(init_sync, dim3(1), dim3(NWG), 0, stream, flags);
    hipLaunchKernelGGL(conv_bf16, dim3(NIH / (256 * 8)), dim3(256), 0, stream, w_ih, wb_ih);
    hipLaunchKernelGGL(conv_bf16, dim3(NIH / (256 * 8)), dim3(256), 0, stream, w_hh, wb_hh);
    hipLaunchKernelGGL(ctrl2_kernel, dim3(NWG), dim3(NTHR), 0, stream,
                       g_emb, w_emb, soft_w, wb_ih, wb_hh, b_ih, b_hh,
                       (float*)d_out, state, flags);
  } else {
    float* ws = (float*)d_ws;
    unsigned long long* bar = (unsigned long long*)(ws + 6 * HD);
    hipLaunchKernelGGL(init_bar, dim3(1), dim3(1), 0, stream, bar);
    hipLaunchKernelGGL(ctrl_kernel, dim3(NWG_FB), dim3(NTHR_FB), 0, stream,
                       g_emb, w_emb, soft_w, w_ih, w_hh, b_ih, b_hh,
                       (float*)d_out, ws);
  }
}

// Round 13
// 851.170 us; speedup vs baseline: 2.8665x; 2.8665x over previous
//
#include <hip/hip_runtime.h>
#include <math.h>

#define HD 2048
#define NACT 16
#define NSTEP 24
#define WL (4*HD*HD)        // per-layer per-matrix elems (16,777,216)
#define NIH (2*WL)          // elems in w_ih (both layers) = 33,554,432

#define NWG 256             // proven co-resident (1 block/CU)
#define NTHR 512            // 8 waves: 1 wave per hidden unit, full-K (R11 shape)
#define NWG_FB 256
#define NTHR_FB 512

typedef float  nf4 __attribute__((ext_vector_type(4)));   // native vec for NT builtins

// ---------------- agent-scope (cross-XCD coherent) access helpers ----------------
__device__ __forceinline__ float ld_agent(const float* p) {
  return __hip_atomic_load(p, __ATOMIC_RELAXED, __HIP_MEMORY_SCOPE_AGENT);
}
__device__ __forceinline__ float2 ld_agent2(const float* p) {   // 8B coherent load
  unsigned long long v = __hip_atomic_load((const unsigned long long*)p,
                                           __ATOMIC_RELAXED, __HIP_MEMORY_SCOPE_AGENT);
  float2 r;
  r.x = __uint_as_float((unsigned)v);
  r.y = __uint_as_float((unsigned)(v >> 32));
  return r;
}
__device__ __forceinline__ void st_agent(float* p, float v) {
  __hip_atomic_store(p, v, __ATOMIC_RELAXED, __HIP_MEMORY_SCOPE_AGENT);
}

// ---------------- threefry2x32-20 (JAX partitionable semantics) ----------------
__device__ __forceinline__ unsigned rotl32(unsigned v, int r) { return (v << r) | (v >> (32 - r)); }

__device__ __forceinline__ void threefry(unsigned k0, unsigned k1, unsigned x0, unsigned x1,
                                         unsigned& o0, unsigned& o1) {
  unsigned ks2 = k0 ^ k1 ^ 0x1BD11BDAu;
#define TFR(r) { x0 += x1; x1 = rotl32(x1, r); x1 ^= x0; }
  x0 += k0; x1 += k1;
  TFR(13) TFR(15) TFR(26) TFR(6)
  x0 += k1;  x1 += ks2 + 1u;
  TFR(17) TFR(29) TFR(16) TFR(24)
  x0 += ks2; x1 += k0 + 2u;
  TFR(13) TFR(15) TFR(26) TFR(6)
  x0 += k0;  x1 += k1 + 3u;
  TFR(17) TFR(29) TFR(16) TFR(24)
  x0 += k1;  x1 += ks2 + 4u;
  TFR(13) TFR(15) TFR(26) TFR(6)
  x0 += ks2; x1 += k0 + 5u;
#undef TFR
  o0 = x0; o1 = x1;
}

__device__ __forceinline__ float sigmoidf(float x) { return 1.0f / (1.0f + expf(-x)); }

// bf16 helpers
__device__ __forceinline__ unsigned f2bf(float f) {          // round-to-nearest-even
  unsigned u = __float_as_uint(f);
  return (u + 0x7fffu + ((u >> 16) & 1u)) >> 16;
}
#define BF_LO(u) __uint_as_float((u) << 16)
#define BF_HI(u) __uint_as_float((u) & 0xffff0000u)

// ---------------- two-level release barrier, fence-free ----------------
// Arrival: one relaxed agent store per wg. Aggregation: ONLY wg 0's wave 0
// polls the 256 arrival flags (64 lanes x 4), then lane 0 publishes the epoch
// to a single release word. All other wgs poll just that one word with a
// single lane -> 256 same-line loads/sweep device-wide instead of 65K
// scattered ones (the R11 flood). Bailout guards -> visible wrong answer
// instead of a hung GPU if co-residency ever failed.
__device__ void grid_bar(unsigned* flags, unsigned* release, unsigned ep) {
  __syncthreads();
  if (threadIdx.x == 0) {
    __hip_atomic_store(&flags[blockIdx.x], ep, __ATOMIC_RELAXED, __HIP_MEMORY_SCOPE_AGENT);
  }
  if (blockIdx.x == 0) {
    if (threadIdx.x < 64) {
      const unsigned* my = flags + threadIdx.x * 4;
      long guard = 0;
      for (;;) {
        unsigned f0 = __hip_atomic_load(my + 0, __ATOMIC_RELAXED, __HIP_MEMORY_SCOPE_AGENT);
        unsigned f1 = __hip_atomic_load(my + 1, __ATOMIC_RELAXED, __HIP_MEMORY_SCOPE_AGENT);
        unsigned f2 = __hip_atomic_load(my + 2, __ATOMIC_RELAXED, __HIP_MEMORY_SCOPE_AGENT);
        unsigned f3 = __hip_atomic_load(my + 3, __ATOMIC_RELAXED, __HIP_MEMORY_SCOPE_AGENT);
        bool ok = (f0 >= ep) && (f1 >= ep) && (f2 >= ep) && (f3 >= ep);
        if (__all(ok)) break;
        if (++guard > 1000000L) break;
        __builtin_amdgcn_s_sleep(2);
      }
      if (threadIdx.x == 0) {
        __hip_atomic_store(release, ep, __ATOMIC_RELAXED, __HIP_MEMORY_SCOPE_AGENT);
      }
    }
  } else {
    if (threadIdx.x == 0) {
      long guard = 0;
      while (__hip_atomic_load(release, __ATOMIC_RELAXED, __HIP_MEMORY_SCOPE_AGENT) < ep &&
             guard < 1000000L) {
        __builtin_amdgcn_s_sleep(4);
        ++guard;
      }
    }
  }
  __syncthreads();
}

// ---------------- logits + categorical sample (redundant per wg, 8 waves) ----------------
__device__ int sample_step(const float* __restrict__ h1g, const float* __restrict__ soft_w,
                           int t, float* lp_out, float* ent_out) {
  __shared__ float s_part[8][NACT];
  __shared__ float s_res[3];
  const int wave = threadIdx.x >> 6;
  const int lane = threadIdx.x & 63;

  float lg[NACT];
#pragma unroll
  for (int a = 0; a < NACT; ++a) lg[a] = 0.0f;
#pragma unroll
  for (int m = 0; m < 2; ++m) {
    int p = wave * 128 + m * 64 + lane;      // pair index; covers elems 2p, 2p+1
    float2 hv = ld_agent2(h1g + p * 2);      // one 8B coherent load
    const float* sw0 = soft_w + (size_t)(p * 2) * NACT;
    const float* sw1 = sw0 + NACT;
#pragma unroll
    for (int h = 0; h < 2; ++h) {
      const float* sw = h ? sw1 : sw0;
      float hvv = h ? hv.y : hv.x;
      float4 r0 = *(const float4*)(sw);
      float4 r1 = *(const float4*)(sw + 4);
      float4 r2 = *(const float4*)(sw + 8);
      float4 r3 = *(const float4*)(sw + 12);
      lg[0]  += hvv * r0.x; lg[1]  += hvv * r0.y; lg[2]  += hvv * r0.z; lg[3]  += hvv * r0.w;
      lg[4]  += hvv * r1.x; lg[5]  += hvv * r1.y; lg[6]  += hvv * r1.z; lg[7]  += hvv * r1.w;
      lg[8]  += hvv * r2.x; lg[9]  += hvv * r2.y; lg[10] += hvv * r2.z; lg[11] += hvv * r2.w;
      lg[12] += hvv * r3.x; lg[13] += hvv * r3.y; lg[14] += hvv * r3.z; lg[15] += hvv * r3.w;
    }
  }
#pragma unroll
  for (int off = 32; off > 0; off >>= 1) {
#pragma unroll
    for (int a = 0; a < NACT; ++a) lg[a] += __shfl_xor(lg[a], off, 64);
  }
  if (lane == 0) {
#pragma unroll
    for (int a = 0; a < NACT; ++a) s_part[wave][a] = lg[a];
  }
  __syncthreads();

  if (wave == 0 && lane < NACT) {
    float logit = 0.0f;
#pragma unroll
    for (int w = 0; w < 8; ++w) logit += s_part[w][lane];

    unsigned kt0, kt1, b0, b1;
    threefry(0u, 42u, 0u, (unsigned)t, kt0, kt1);
    threefry(kt0, kt1, 0u, (unsigned)lane, b0, b1);
    unsigned bits = b0 ^ b1;

    const float tiny = 1.17549435e-38f;
    float u = __uint_as_float((bits >> 9) | 0x3f800000u) - 1.0f;  // [0,1)
    u = fmaxf(tiny, u + tiny);
    float gmb = -logf(-logf(u));
    float z = logit + gmb;

    int idx = lane; float zz = z;
#pragma unroll
    for (int off = 8; off > 0; off >>= 1) {
      float oz = __shfl_xor(zz, off, NACT);
      int   oi = __shfl_xor(idx, off, NACT);
      if (oz > zz || (oz == zz && oi < idx)) { zz = oz; idx = oi; }
    }
    float mx = logit;
#pragma unroll
    for (int off = 8; off > 0; off >>= 1) mx = fmaxf(mx, __shfl_xor(mx, off, NACT));
    float sh = logit - mx;
    float se = expf(sh);
#pragma unroll
    for (int off = 8; off > 0; off >>= 1) se += __shfl_xor(se, off, NACT);
    float lp = sh - logf(se);
    float term = expf(lp) * lp;
#pragma unroll
    for (int off = 8; off > 0; off >>= 1) term += __shfl_xor(term, off, NACT);
    float lp_sel = __shfl(lp, idx, NACT);
    if (lane == 0) { s_res[0] = (float)idx; s_res[1] = lp_sel; s_res[2] = -term; }
  }
  __syncthreads();
  int act = (int)s_res[0];
  *lp_out = s_res[1];
  *ent_out = s_res[2];
  return act;
}

// =======================================================================
//                     FAST PATH: bf16 weights in d_ws
// =======================================================================

// f32 -> bf16 conversion, 8 elems/thread. NT loads for the single-use f32 stream.
__global__ void __launch_bounds__(256) conv_bf16(const float* __restrict__ src,
                                                 unsigned* __restrict__ dst) {
  size_t i = ((size_t)blockIdx.x * blockDim.x + threadIdx.x) * 8;
  const nf4* s4 = (const nf4*)(src + i);
  nf4 a = __builtin_nontemporal_load(s4);
  nf4 b = __builtin_nontemporal_load(s4 + 1);
  uint4 o;
  o.x = (f2bf(a.y) << 16) | f2bf(a.x);
  o.y = (f2bf(a.w) << 16) | f2bf(a.z);
  o.z = (f2bf(b.y) << 16) | f2bf(b.x);
  o.w = (f2bf(b.w) << 16) | f2bf(b.z);
  *(uint4*)(dst + i / 2) = o;
}

// one LSTM layer, bf16 weights. 512 threads: wave = unit (8 units/wg),
// full 2048-dot per wave over both matrices (R11's proven no-spill shape).
// x/h staged into LDS via 8B coherent loads, then register-staged as DENSE
// float4 (16B stride -> conflict-free). Weights read as uint2 (8 B/lane).
__device__ void layer_bf16(const unsigned* __restrict__ wiL, const unsigned* __restrict__ whL,
                           const float* __restrict__ bihL, const float* __restrict__ bhhL,
                           const float* __restrict__ x, bool x_is_shared_state,
                           const float* __restrict__ hin,
                           float* __restrict__ hout, float* __restrict__ c,
                           float* s_x, float* s_h) {
  const int tid = threadIdx.x;
  // ---- cooperative stage of x (2048) and h (2048) into LDS ----
  if (x_is_shared_state) {
    float2 a = ld_agent2(x + tid * 2);
    float2 b = ld_agent2(x + 1024 + tid * 2);
    *(float2*)(s_x + tid * 2) = a;
    *(float2*)(s_x + 1024 + tid * 2) = b;
  } else {
    *(float4*)(s_x + tid * 4) = *(const float4*)(x + tid * 4);
  }
  {
    float2 ha = ld_agent2(hin + tid * 2);
    float2 hb = ld_agent2(hin + 1024 + tid * 2);
    *(float2*)(s_h + tid * 2) = ha;
    *(float2*)(s_h + 1024 + tid * 2) = hb;
  }
  __syncthreads();

  const int wave = tid >> 6;
  const int lane = tid & 63;
  const int j = (int)blockIdx.x * 8 + wave;   // hidden unit owned by this wave

  // register-stage: chunk k covers elems [k*256 + lane*4, +4)  (dense float4)
  float4 xv[8], hv[8];
#pragma unroll
  for (int k = 0; k < 8; ++k) {
    int e = k * 256 + lane * 4;
    xv[k] = *(const float4*)(s_x + e);
    hv[k] = *(const float4*)(s_h + e);
  }

  float acc[4];
#pragma unroll
  for (int g = 0; g < 4; ++g) {
    const unsigned* wi = wiL + ((size_t)(g * HD + j) * HD >> 1);  // uint = 2 bf16
    const unsigned* wh = whL + ((size_t)(g * HD + j) * HD >> 1);
    float si = 0.0f, sh2 = 0.0f;
#pragma unroll
    for (int k = 0; k < 8; ++k) {
      int e2 = k * 128 + lane * 2;     // uint offset (uint2 = 4 bf16 = lane's 4 elems)
      uint2 qa = *(const uint2*)(wi + e2);
      uint2 qb = *(const uint2*)(wh + e2);
      si  += BF_LO(qa.x) * xv[k].x + BF_HI(qa.x) * xv[k].y;
      si  += BF_LO(qa.y) * xv[k].z + BF_HI(qa.y) * xv[k].w;
      sh2 += BF_LO(qb.x) * hv[k].x + BF_HI(qb.x) * hv[k].y;
      sh2 += BF_LO(qb.y) * hv[k].z + BF_HI(qb.y) * hv[k].w;
    }
    acc[g] = si + sh2;
  }
#pragma unroll
  for (int off = 32; off > 0; off >>= 1) {
#pragma unroll
    for (int g = 0; g < 4; ++g) acc[g] += __shfl_xor(acc[g], off, 64);
  }
  if (lane == 0) {
    float gi = acc[0] + bihL[j]          + bhhL[j];
    float gf = acc[1] + bihL[HD + j]     + bhhL[HD + j];
    float gg = acc[2] + bihL[2 * HD + j] + bhhL[2 * HD + j];
    float go = acc[3] + bihL[3 * HD + j] + bhhL[3 * HD + j];
    float cn = sigmoidf(gf) * c[j] + sigmoidf(gi) * tanhf(gg);
    c[j] = cn;                                     // wg-private (same CU)
    st_agent(&hout[j], sigmoidf(go) * tanhf(cn));  // cross-wg coherent
  }
}

__global__ void __launch_bounds__(NTHR) ctrl2_kernel(
    const float* __restrict__ g_emb, const float* __restrict__ w_emb,
    const float* __restrict__ soft_w,
    const unsigned* __restrict__ wb_ih, const unsigned* __restrict__ wb_hh,
    const float* __restrict__ b_ih, const float* __restrict__ b_hh,
    float* __restrict__ out, float* __restrict__ state,
    unsigned* __restrict__ flags, unsigned* __restrict__ release) {
  __shared__ float s_x[HD];
  __shared__ float s_h[HD];
  float* h0 = state;            // [2][HD] ping-pong
  float* h1 = state + 2 * HD;   // [2][HD] ping-pong
  float* c0 = state + 4 * HD;
  float* c1 = state + 5 * HD;

  if (threadIdx.x < 8) {
    int j = (int)blockIdx.x * 8 + (int)threadIdx.x;
    st_agent(&h0[j], 0.0f); st_agent(&h1[j], 0.0f);
    c0[j] = 0.0f; c1[j] = 0.0f;
  }
  unsigned ep = 1;
  grid_bar(flags, release, ep++);

  const unsigned* wi0 = wb_ih;             const unsigned* wh0 = wb_hh;
  const unsigned* wi1 = wb_ih + WL / 2;    const unsigned* wh1 = wb_hh + WL / 2;

  const float* x = g_emb;
  for (int t = 0; t < NSTEP; ++t) {
    int q = t & 1;
    layer_bf16(wi0, wh0, b_ih, b_hh, x, /*x shared=*/false,
               h0 + q * HD, h0 + (1 - q) * HD, c0, s_x, s_h);
    grid_bar(flags, release, ep++);
    layer_bf16(wi1, wh1, b_ih + 4 * HD, b_hh + 4 * HD,
               h0 + (1 - q) * HD, /*x shared=*/true,
               h1 + q * HD, h1 + (1 - q) * HD, c1, s_x, s_h);
    grid_bar(flags, release, ep++);
    float lp, en;
    int act = sample_step(h1 + (1 - q) * HD, soft_w, t, &lp, &en);
    if (blockIdx.x == 0 && threadIdx.x == 0) {
      out[t] = (float)act;
      out[NSTEP + t] = lp;
      out[2 * NSTEP + t] = en;
    }
    x = w_emb + (size_t)act * HD;
  }
}

// =======================================================================
//          FALLBACK PATH: f32 weights direct (round-5-proven, 256x512)
// =======================================================================

__device__ void grid_bar_ctr(unsigned long long* ctr, unsigned long long target) {
  __syncthreads();
  if (threadIdx.x == 0) {
    __builtin_amdgcn_fence(__ATOMIC_SEQ_CST, "agent");
    __hip_atomic_fetch_add(ctr, 1ull, __ATOMIC_RELAXED, __HIP_MEMORY_SCOPE_AGENT);
    long guard = 0;
    while (__hip_atomic_load(ctr, __ATOMIC_RELAXED, __HIP_MEMORY_SCOPE_AGENT) < target &&
           guard < 20000000L) {
      __builtin_amdgcn_s_sleep(2);
      ++guard;
    }
    __builtin_amdgcn_fence(__ATOMIC_SEQ_CST, "agent");
  }
  __syncthreads();
}

__device__ int sample_step8(const float* __restrict__ h1g, const float* __restrict__ soft_w,
                            int t, float* lp_out, float* ent_out) {
  __shared__ float s_part[8][NACT];
  __shared__ float s_res[3];
  const int wave = threadIdx.x >> 6;
  const int lane = threadIdx.x & 63;

  float lg[NACT];
#pragma unroll
  for (int a = 0; a < NACT; ++a) lg[a] = 0.0f;
#pragma unroll
  for (int m = 0; m < 4; ++m) {
    int e = wave * 256 + m * 64 + lane;
    float hv = h1g[e];
    const float* sw = soft_w + (size_t)e * NACT;
    float4 r0 = *(const float4*)(sw);
    float4 r1 = *(const float4*)(sw + 4);
    float4 r2 = *(const float4*)(sw + 8);
    float4 r3 = *(const float4*)(sw + 12);
    lg[0]  += hv * r0.x; lg[1]  += hv * r0.y; lg[2]  += hv * r0.z; lg[3]  += hv * r0.w;
    lg[4]  += hv * r1.x; lg[5]  += hv * r1.y; lg[6]  += hv * r1.z; lg[7]  += hv * r1.w;
    lg[8]  += hv * r2.x; lg[9]  += hv * r2.y; lg[10] += hv * r2.z; lg[11] += hv * r2.w;
    lg[12] += hv * r3.x; lg[13] += hv * r3.y; lg[14] += hv * r3.z; lg[15] += hv * r3.w;
  }
#pragma unroll
  for (int off = 32; off > 0; off >>= 1) {
#pragma unroll
    for (int a = 0; a < NACT; ++a) lg[a] += __shfl_xor(lg[a], off, 64);
  }
  if (lane == 0) {
#pragma unroll
    for (int a = 0; a < NACT; ++a) s_part[wave][a] = lg[a];
  }
  __syncthreads();

  if (wave == 0 && lane < NACT) {
    float logit = 0.0f;
#pragma unroll
    for (int w = 0; w < 8; ++w) logit += s_part[w][lane];
    unsigned kt0, kt1, b0, b1;
    threefry(0u, 42u, 0u, (unsigned)t, kt0, kt1);
    threefry(kt0, kt1, 0u, (unsigned)lane, b0, b1);
    unsigned bits = b0 ^ b1;
    const float tiny = 1.17549435e-38f;
    float u = __uint_as_float((bits >> 9) | 0x3f800000u) - 1.0f;
    u = fmaxf(tiny, u + tiny);
    float gmb = -logf(-logf(u));
    float z = logit + gmb;
    int idx = lane; float zz = z;
#pragma unroll
    for (int off = 8; off > 0; off >>= 1) {
      float oz = __shfl_xor(zz, off, NACT);
      int   oi = __shfl_xor(idx, off, NACT);
      if (oz > zz || (oz == zz && oi < idx)) { zz = oz; idx = oi; }
    }
    float mx = logit;
#pragma unroll
    for (int off = 8; off > 0; off >>= 1) mx = fmaxf(mx, __shfl_xor(mx, off, NACT));
    float sh = logit - mx;
    float se = expf(sh);
#pragma unroll
    for (int off = 8; off > 0; off >>= 1) se += __shfl_xor(se, off, NACT);
    float lp = sh - logf(se);
    float term = expf(lp) * lp;
#pragma unroll
    for (int off = 8; off > 0; off >>= 1) term += __shfl_xor(term, off, NACT);
    float lp_sel = __shfl(lp, idx, NACT);
    if (lane == 0) { s_res[0] = (float)idx; s_res[1] = lp_sel; s_res[2] = -term; }
  }
  __syncthreads();
  int act = (int)s_res[0];
  *lp_out = s_res[1];
  *ent_out = s_res[2];
  return act;
}

__device__ void lstm_layer(const float* __restrict__ Wih, const float* __restrict__ Whh,
                           const float* __restrict__ bih, const float* __restrict__ bhh,
                           const float* __restrict__ x, const float* __restrict__ hin,
                           float* __restrict__ hout, float* __restrict__ c) {
  const int wave = threadIdx.x >> 6;
  const int lane = threadIdx.x & 63;
  const int j = (int)blockIdx.x * 8 + wave;

  float4 xv[8], hv[8];
#pragma unroll
  for (int k = 0; k < 8; ++k) {
    int e = k * 256 + lane * 4;
    xv[k] = *(const float4*)(x + e);
    hv[k] = *(const float4*)(hin + e);
  }
  float acc[4];
#pragma unroll
  for (int g = 0; g < 4; ++g) {
    const float* wi = Wih + (size_t)(g * HD + j) * HD;
    const float* wh = Whh + (size_t)(g * HD + j) * HD;
    float s = 0.0f;
#pragma unroll
    for (int k = 0; k < 8; ++k) {
      int e = k * 256 + lane * 4;
      float4 a4 = *(const float4*)(wi + e);
      float4 b4 = *(const float4*)(wh + e);
      s += a4.x * xv[k].x; s += a4.y * xv[k].y; s += a4.z * xv[k].z; s += a4.w * xv[k].w;
      s += b4.x * hv[k].x; s += b4.y * hv[k].y; s += b4.z * hv[k].z; s += b4.w * hv[k].w;
    }
    acc[g] = s;
  }
#pragma unroll
  for (int off = 32; off > 0; off >>= 1) {
#pragma unroll
    for (int g = 0; g < 4; ++g) acc[g] += __shfl_xor(acc[g], off, 64);
  }
  if (lane == 0) {
    float gi = acc[0] + bih[j]          + bhh[j];
    float gf = acc[1] + bih[HD + j]     + bhh[HD + j];
    float gg = acc[2] + bih[2 * HD + j] + bhh[2 * HD + j];
    float go = acc[3] + bih[3 * HD + j] + bhh[3 * HD + j];
    float cn = sigmoidf(gf) * c[j] + sigmoidf(gi) * tanhf(gg);
    c[j] = cn;
    hout[j] = sigmoidf(go) * tanhf(cn);
  }
}

__global__ void __launch_bounds__(NTHR_FB) ctrl_kernel(
    const float* __restrict__ g_emb, const float* __restrict__ w_emb,
    const float* __restrict__ soft_w, const float* __restrict__ w_ih,
    const float* __restrict__ w_hh, const float* __restrict__ b_ih,
    const float* __restrict__ b_hh, float* __restrict__ out, float* __restrict__ ws) {
  float* h0 = ws;
  float* h1 = ws + 2 * HD;
  float* c0 = ws + 4 * HD;
  float* c1 = ws + 5 * HD;
  unsigned long long* bar = (unsigned long long*)(ws + 6 * HD);

  if (threadIdx.x < 8) {
    int j = (int)blockIdx.x * 8 + (int)threadIdx.x;
    h0[j] = 0.0f; h1[j] = 0.0f; c0[j] = 0.0f; c1[j] = 0.0f;
  }
  unsigned long long ep = 1;
  grid_bar_ctr(bar, (ep++) * NWG_FB);

  const float* x = g_emb;
  for (int t = 0; t < NSTEP; ++t) {
    int q = t & 1;
    lstm_layer(w_ih, w_hh, b_ih, b_hh, x, h0 + q * HD, h0 + (1 - q) * HD, c0);
    grid_bar_ctr(bar, (ep++) * NWG_FB);
    lstm_layer(w_ih + WL, w_hh + WL, b_ih + 4 * HD, b_hh + 4 * HD,
               h0 + (1 - q) * HD, h1 + q * HD, h1 + (1 - q) * HD, c1);
    grid_bar_ctr(bar, (ep++) * NWG_FB);
    float lp, en;
    int act = sample_step8(h1 + (1 - q) * HD, soft_w, t, &lp, &en);
    if (blockIdx.x == 0 && threadIdx.x == 0) {
      out[t] = (float)act;
      out[NSTEP + t] = lp;
      out[2 * NSTEP + t] = en;
    }
    x = w_emb + (size_t)act * HD;
  }
}

__global__ void init_sync(unsigned* flags) {            // zero flags + release area
  flags[threadIdx.x] = 0u;
}
__global__ void init_bar(unsigned long long* bar) { *bar = 0ull; }

extern "C" void kernel_launch(void* const* d_in, const int* in_sizes, int n_in,
                              void* d_out, int out_size, void* d_ws, size_t ws_size,
                              hipStream_t stream) {
  const float* g_emb  = (const float*)d_in[0];
  const float* w_emb  = (const float*)d_in[1];
  const float* soft_w = (const float*)d_in[2];
  const float* w_ih   = (const float*)d_in[3];
  const float* w_hh   = (const float*)d_in[4];
  const float* b_ih   = (const float*)d_in[5];
  const float* b_hh   = (const float*)d_in[6];

  const size_t wbytes = (size_t)NIH * 2 * sizeof(unsigned short);  // 134,217,728
  const size_t need = wbytes + (size_t)6 * HD * sizeof(float) + 512 * sizeof(unsigned) + 64;

  if (ws_size >= need) {
    unsigned* wb_ih = (unsigned*)d_ws;               // NIH bf16 = NIH/2 uints
    unsigned* wb_hh = wb_ih + NIH / 2;
    float* state = (float*)((char*)d_ws + wbytes);
    unsigned* flags = (unsigned*)(state + 6 * HD);   // 256 arrival flags
    unsigned* release = flags + 320;                 // own cache line, within 512 zeroed

    hipLaunchKernelGGL(init_sync, dim3(1), dim3(512), 0, stream, flags);
    hipLaunchKernelGGL(conv_bf16, dim3(NIH / (256 * 8)), dim3(256), 0, stream, w_ih, wb_ih);
    hipLaunchKernelGGL(conv_bf16, dim3(NIH / (256 * 8)), dim3(256), 0, stream, w_hh, wb_hh);
    hipLaunchKernelGGL(ctrl2_kernel, dim3(NWG), dim3(NTHR), 0, stream,
                       g_emb, w_emb, soft_w, wb_ih, wb_hh, b_ih, b_hh,
                       (float*)d_out, state, flags, release);
  } else {
    float* ws = (float*)d_ws;
    unsigned long long* bar = (unsigned long long*)(ws + 6 * HD);
    hipLaunchKernelGGL(init_bar, dim3(1), dim3(1), 0, stream, bar);
    hipLaunchKernelGGL(ctrl_kernel, dim3(NWG_FB), dim3(NTHR_FB), 0, stream,
                       g_emb, w_emb, soft_w, w_ih, w_hh, b_ih, b_hh,
                       (float*)d_out, ws);
  }
}